// Round 1
// baseline (23.751 us; speedup 1.0000x reference)
//
#include <hip/hip_runtime.h>
#include <cmath>

#define IMG_H 1080
#define IMG_W 1920
#define NPIX (IMG_H * IMG_W)     // 2,073,600 = 8100 * 256
#define BLOCK 256
#define NBLOCKS (NPIX / BLOCK)   // 8100

__global__ __launch_bounds__(BLOCK) void pose_fwd_kernel(
    const float* __restrict__ x,
    const float* __restrict__ ref_img,
    const float* __restrict__ ref_depth,
    const float* __restrict__ trg_img,
    const float* __restrict__ K,
    float* __restrict__ out)
{
    __shared__ float sRt[12];          // R (row-major 9) + t (3)
    __shared__ float sout[BLOCK * 7];  // output transpose staging

    const int tid = threadIdx.x;

    // ---- se3_exp(x): one thread per block (uniform 12-float result) ----
    if (tid == 0) {
        const float wx = x[0], wy = x[1], wz = x[2];
        const float vx = x[3], vy = x[4], vz = x[5];
        const float t2 = wx * wx + wy * wy + wz * wz;
        float A, B, C;
        if (t2 < 1e-8f) {
            A = 1.0f - t2 / 6.0f;
            B = 0.5f - t2 / 24.0f;
            C = 1.0f / 6.0f - t2 / 120.0f;
        } else {
            const float th = sqrtf(t2);
            const float s = sinf(th), c = cosf(th);
            A = s / th;
            B = (1.0f - c) / t2;
            C = (th - s) / (t2 * th);
        }
        // W^2 (symmetric)
        const float W00 = -(wy * wy + wz * wz), W01 = wx * wy, W02 = wx * wz;
        const float W11 = -(wx * wx + wz * wz), W12 = wy * wz;
        const float W22 = -(wx * wx + wy * wy);
        // R = I + A*hat(w) + B*W2
        sRt[0] = 1.0f + B * W00;        sRt[1] = A * (-wz) + B * W01;  sRt[2] = A * wy + B * W02;
        sRt[3] = A * wz + B * W01;      sRt[4] = 1.0f + B * W11;       sRt[5] = A * (-wx) + B * W12;
        sRt[6] = A * (-wy) + B * W02;   sRt[7] = A * wx + B * W12;     sRt[8] = 1.0f + B * W22;
        // V = I + B*hat(w) + C*W2 ; t = V @ v
        const float V00 = 1.0f + C * W00,      V01 = B * (-wz) + C * W01, V02 = B * wy + C * W02;
        const float V10 = B * wz + C * W01,    V11 = 1.0f + C * W11,      V12 = B * (-wx) + C * W12;
        const float V20 = B * (-wy) + C * W02, V21 = B * wx + C * W12,    V22 = 1.0f + C * W22;
        sRt[9]  = V00 * vx + V01 * vy + V02 * vz;
        sRt[10] = V10 * vx + V11 * vy + V12 * vz;
        sRt[11] = V20 * vx + V21 * vy + V22 * vz;
    }
    __syncthreads();

    const unsigned n = blockIdx.x * BLOCK + tid;   // grid is exact, no tail
    const int v = (int)(n / IMG_W);
    const int u = (int)(n - (unsigned)v * IMG_W);

    // intrinsics (uniform scalar loads)
    const float k00 = K[0], k01 = K[1], k02 = K[2];
    const float k10 = K[3], k11 = K[4], k12 = K[5];
    const float k20 = K[6], k21 = K[7], k22 = K[8];
    const float fx = k00, fy = k11, cx = k02, cy = k12;

    const float z = ref_depth[n];
    const float X = ((float)u - cx) * z / fx;
    const float Y = ((float)v - cy) * z / fy;

    const float R0 = sRt[0], R1 = sRt[1], R2 = sRt[2];
    const float R3 = sRt[3], R4 = sRt[4], R5 = sRt[5];
    const float R6 = sRt[6], R7 = sRt[7], R8 = sRt[8];
    const float tx = sRt[9], ty = sRt[10], tz = sRt[11];

    // p = R @ pts + t
    const float px = R0 * X + R1 * Y + R2 * z + tx;
    const float py = R3 * X + R4 * Y + R5 * z + ty;
    const float pz = R6 * X + R7 * Y + R8 * z + tz;

    // proj = K @ p
    const float p0 = k00 * px + k01 * py + k02 * pz;
    const float p1 = k10 * px + k11 * py + k12 * pz;
    const float p2 = k20 * px + k21 * py + k22 * pz;

    const float uw = p0 / p2;
    const float vw = p1 / p2;
    const int ui = (int)uw;  // trunc toward zero == astype(int32)
    const int vi = (int)vw;
    const bool valid = (vi < IMG_H) && (ui < IMG_W) && (vi > 0) && (ui > 0);
    const int cu = min(max(ui, 0), IMG_W - 1);
    const int cv = min(max(vi, 0), IMG_H - 1);
    const float warped = ref_img[cv * IMG_W + cu];
    const float res = valid ? (warped - trg_img[n]) : 0.0f;

    // Sobel of trg (cross-correlation), zero on 2-pixel border
    float gx = 0.0f, gy = 0.0f;
    if (v >= 2 && v <= IMG_H - 3 && u >= 2 && u <= IMG_W - 3) {
        const float* tp = trg_img + (size_t)(v - 1) * IMG_W + (u - 1);
        const float t00 = tp[0],          t01 = tp[1],          t02 = tp[2];
        const float t10 = tp[IMG_W],                            t12 = tp[IMG_W + 2];
        const float t20 = tp[2 * IMG_W],  t21 = tp[2 * IMG_W + 1], t22 = tp[2 * IMG_W + 2];
        gx = 0.125f * (t02 - t00) + 0.25f * (t12 - t10) + 0.125f * (t22 - t20);
        gy = 0.125f * (t20 - t00) + 0.25f * (t21 - t01) + 0.125f * (t22 - t02);
    }

    // J = gx * r0 + gy * r1   (note: reference uses fx in BOTH rows)
    const float zi = 1.0f / z;
    const float zi2 = zi * zi;
    const float fzi = fx * zi;
    float J0 = 0.0f, J1 = 0.0f, J2 = 0.0f, J3 = 0.0f, J4 = 0.0f, J5 = 0.0f;
    if (valid) {
        const float xy = X * Y * zi2;
        J0 = gx * (-fx * xy)                 + gy * (-fx * (1.0f + Y * Y * zi2));
        J1 = gx * ( fx * (1.0f + X * X * zi2)) + gy * ( fx * xy);
        J2 = gx * (-fx * Y * zi)             + gy * ( fx * X * zi);
        J3 = gx * fzi;
        J4 = gy * fzi;
        J5 = gx * (-fx * X * zi2)            + gy * (-fx * Y * zi2);
    }

    // ---- LDS transpose so global stores are fully coalesced ----
    sout[tid * 7 + 0] = res;
    sout[tid * 7 + 1] = J0;
    sout[tid * 7 + 2] = J1;
    sout[tid * 7 + 3] = J2;
    sout[tid * 7 + 4] = J3;
    sout[tid * 7 + 5] = J4;
    sout[tid * 7 + 6] = J5;
    __syncthreads();

    const int base = blockIdx.x * (BLOCK * 7);
#pragma unroll
    for (int j = 0; j < 7; ++j) {
        out[base + j * BLOCK + tid] = sout[j * BLOCK + tid];
    }
}

extern "C" void kernel_launch(void* const* d_in, const int* in_sizes, int n_in,
                              void* d_out, int out_size, void* d_ws, size_t ws_size,
                              hipStream_t stream) {
    const float* x          = (const float*)d_in[0];
    const float* ref_img    = (const float*)d_in[1];
    const float* ref_depth  = (const float*)d_in[2];
    const float* trg_img    = (const float*)d_in[3];
    const float* intrinsics = (const float*)d_in[4];
    float* out = (float*)d_out;

    pose_fwd_kernel<<<NBLOCKS, BLOCK, 0, stream>>>(
        x, ref_img, ref_depth, trg_img, intrinsics, out);
}